// Round 11
// baseline (14360.315 us; speedup 1.0000x reference)
//
#include <hip/hip_runtime.h>
#include <math.h>

typedef unsigned int u32;

#define T_SEQ   2048
#define NWG     256

// ---------------- workspace layout (bytes) ----------------
#define OFF_HBUF   0            // float[2][32][512] = 131072
#define OFF_CNT    131072       // u32[4][8][32] (32 sub-counters, 128B apart) = 4096
#define OFF_LASTH  135168       // float[32][512] = 65536
#define WS_NEED    200704ull

// ---------------- fallback (round-2 proven) layout ----------------
#define FB_OFF_HBUF   0
#define FB_OFF_ARRIVE 131072
#define FB_OFF_LASTH  131328

#define DYN_LDS_BYTES 148480    // Wl 131072 + Hl 16384 + gsc 1024

__device__ __forceinline__ float sigm(float x) { return 1.0f / (1.0f + expf(-x)); }

// ---- LLC-coherent accessors (sc0 sc1 = bypass L1 + XCD L2); r8/r10-proven ----
__device__ __forceinline__ float4 ldg4s(const float* p) {
  float4 v;
  asm volatile("global_load_dwordx4 %0, %1, off sc0 sc1" : "=v"(v) : "v"(p) : "memory");
  return v;
}
__device__ __forceinline__ void stg1fs(float* p, float v) {
  asm volatile("global_store_dword %0, %1, off sc0 sc1" :: "v"(p), "v"(v) : "memory");
}

// =====================================================================
// Sequential LSTM v6: r10 structure (passed, 13.6 ms) + serial-chain cuts:
//  - per-bg arrive counter SPLIT into 8 sub-counters (128B apart): 8 adds
//    each per step instead of 64 on one line (RMW serialization /8).
//    Consumers poll with lanes 0..7 (__all over 8-lane exec), target 8t.
//  - s_sleep(1) poll quantum (was 4).
//  - poll moved between emb jb{0,1} and jb{2,3} (detect overlaps emb).
//  - h sc0sc1 loads issued BEFORE emb jb{2,3}; vmcnt(0) after (LLC latency
//    hidden under ~half the emb phase).
// Everything else byte-identical to r10 (W in LDS 128KB swizzled, no spill;
// h dedup via swizzled Hl; 4x shfl_xor k-reduction; watchdog).
// =====================================================================
__global__ void __launch_bounds__(256, 1)
lstm_seq(const int* __restrict__ x, const int* __restrict__ attn,
         const float* __restrict__ emb,
         const float* __restrict__ Wih, const float* __restrict__ Whh,
         const float* __restrict__ bih, const float* __restrict__ bhh,
         float* __restrict__ hbuf, u32* __restrict__ counters,
         float* __restrict__ lasth)
{
  extern __shared__ __align__(16) char smem[];
  float4* Wl4 = (float4*)smem;                       // [32 rows][256 chunks] swizzled
  float4* Hl4 = (float4*)(smem + 131072);            // [8 b][128 chunks] swizzled
  float*  gsc = (float*)(smem + 131072 + 16384);     // [32][8]
  __shared__ int s_dead;

  const int tid = threadIdx.x, bid = blockIdx.x;
  const int ug = bid >> 2, bg = bid & 3;
  const int wv = tid >> 6, lane = tid & 63;
  const int kg = lane >> 2, inner = lane & 3;
  const int rowg = wv * 2 + (inner >> 1);            // 0..7 -> rows rowg*4..+4
  const int bbase = (inner & 1) * 4;                 // local batches bbase..+4

  u32* cntb = counters + bg * 256;                   // 8 sub-counters, 32 u32 (128B) apart
  u32* mycnt = cntb + (ug & 7) * 32;                 // this WG posts here

  // ---- W slice -> LDS, swizzled (one-time) ----
#pragma unroll
  for (int k = 0; k < 32; ++k) {
    int cf = tid + k * 256;            // 0..8191
    int r  = cf >> 8, c = cf & 255;
    int R  = (r >> 3) * 512 + ug * 8 + (r & 7);      // gate*512 + unit
    const float* src = (c < 128) ? (Wih + (size_t)R * 512 + c * 4)
                                 : (Whh + (size_t)R * 512 + (c - 128) * 4);
    float4 v = *(const float4*)src;
    int p = r * 256 + (c & ~7) + (((c & 7) + ((c >> 3) & 15) + (r >> 2)) & 7);
    Wl4[p] = v;
  }

  // ---- lengths (partials in gsc as [32 chunks][8 b]) ----
  {
    int b = tid & 7, c = tid >> 3;     // c in [0,32)
    const int4* ap = (const int4*)(attn + (size_t)(bg * 8 + b) * 2048 + c * 64);
    int s = 0;
#pragma unroll
    for (int k = 0; k < 16; ++k) { int4 a = ap[k]; s += a.x + a.y + a.z + a.w; }
    gsc[c * 8 + b] = (float)s;
  }
  if (tid == 0) s_dead = 0;
  __syncthreads();
  int len = 0; float c_reg = 0.f;
  float bI = 0, bF = 0, bG = 0, bO = 0;
  if (tid < 64) {
    int b = tid & 7, uu = tid >> 3;
    int s = 0;
#pragma unroll
    for (int c = 0; c < 32; ++c) s += (int)gsc[c * 8 + b];
    len = s - 1; if (len < 0) len = T_SEQ - 1;
    int gu = ug * 8 + uu;
    bI = bih[gu]        + bhh[gu];
    bF = bih[512 + gu]  + bhh[512 + gu];
    bG = bih[1024 + gu] + bhh[1024 + gu];
    bO = bih[1536 + gu] + bhh[1536 + gu];
  }
  __syncthreads();   // gsc reusable

  bool dead = false;
  float4 w[4][8];    // per-phase W fragment: 4 rows x 32 floats (128 VGPR)

  for (int t = 0; t < T_SEQ; ++t) {
    float acc[4][4];
#pragma unroll
    for (int i = 0; i < 4; ++i) { acc[i][0] = 0.f; acc[i][1] = 0.f; acc[i][2] = 0.f; acc[i][3] = 0.f; }

    // ---- W fragment, phase 0 ----
#pragma unroll
    for (int i = 0; i < 4; ++i) {
      int r = rowg * 4 + i;
#pragma unroll
      for (int q = 0; q < 8; ++q)
        w[i][q] = Wl4[r * 256 + kg * 8 + ((q + kg + rowg) & 7)];
    }

    // ---- emb jb {0,1} (h-independent) ----
#pragma unroll
    for (int jb = 0; jb < 2; ++jb) {
      int xr = x[(size_t)(bg * 8 + bbase + jb) * 2048 + t];
      const float4* ep = (const float4*)(emb + (size_t)xr * 512 + kg * 32);
      float4 e[8];
#pragma unroll
      for (int q = 0; q < 8; ++q) e[q] = ep[q];
#pragma unroll
      for (int q = 0; q < 8; ++q)
#pragma unroll
        for (int i = 0; i < 4; ++i) {
          acc[i][jb] += w[i][q].x * e[q].x; acc[i][jb] += w[i][q].y * e[q].y;
          acc[i][jb] += w[i][q].z * e[q].z; acc[i][jb] += w[i][q].w * e[q].w;
        }
    }

    // ---- barrier: lanes 0..7 poll the 8 sub-counters (target 8t each) ----
    if (tid < 8 && !dead) {
      const u32 target = (u32)(t << 3);
      const u32* myc = cntb + tid * 32;
      int it = 0;
      while (true) {
        u32 v = __hip_atomic_load(myc, __ATOMIC_RELAXED, __HIP_MEMORY_SCOPE_AGENT);
        if (__all((int)v >= (int)target)) break;
        if (++it > (1 << 16)) { s_dead = 1; break; }   // watchdog: no hang
        __builtin_amdgcn_s_sleep(1);
      }
    }
    __syncthreads();
    if (s_dead) dead = true;

    // ---- issue h loads NOW (sc0sc1); latency hides under emb jb {2,3} ----
    float4 hv[4];
    int pp[4];
    {
      const float* hsrc = hbuf + (((t + 1) & 1) << 14) + (size_t)(bg * 8) * 512;
#pragma unroll
      for (int k = 0; k < 4; ++k) {
        int cf = tid + k * 256;        // 0..1023
        int b = cf >> 7, c = cf & 127;
        hv[k] = ldg4s(hsrc + (size_t)b * 512 + c * 4);
        pp[k] = b * 128 + (c & ~7) + (((c & 7) + (c >> 3) + b) & 7);
      }
    }

    // ---- emb jb {2,3} ----
#pragma unroll
    for (int jb = 2; jb < 4; ++jb) {
      int xr = x[(size_t)(bg * 8 + bbase + jb) * 2048 + t];
      const float4* ep = (const float4*)(emb + (size_t)xr * 512 + kg * 32);
      float4 e[8];
#pragma unroll
      for (int q = 0; q < 8; ++q) e[q] = ep[q];
#pragma unroll
      for (int q = 0; q < 8; ++q)
#pragma unroll
        for (int i = 0; i < 4; ++i) {
          acc[i][jb] += w[i][q].x * e[q].x; acc[i][jb] += w[i][q].y * e[q].y;
          acc[i][jb] += w[i][q].z * e[q].z; acc[i][jb] += w[i][q].w * e[q].w;
        }
    }

    // ---- drain h loads, stage into swizzled Hl ----
    asm volatile("s_waitcnt vmcnt(0)" ::: "memory");
    __builtin_amdgcn_sched_barrier(0);
#pragma unroll
    for (int k = 0; k < 4; ++k) Hl4[pp[k]] = hv[k];
    __syncthreads();

    // ---- h phase: W(phase 1) from LDS, u from Hl ----
#pragma unroll
    for (int i = 0; i < 4; ++i) {
      int r = rowg * 4 + i;
#pragma unroll
      for (int q = 0; q < 8; ++q)
        w[i][q] = Wl4[r * 256 + 128 + kg * 8 + ((q + kg + rowg) & 7)];
    }
#pragma unroll
    for (int jb = 0; jb < 4; ++jb) {
      int bl = bbase + jb;
      float4 e[8];
#pragma unroll
      for (int q = 0; q < 8; ++q)
        e[q] = Hl4[bl * 128 + kg * 8 + ((q + kg + bl) & 7)];
#pragma unroll
      for (int q = 0; q < 8; ++q)
#pragma unroll
        for (int i = 0; i < 4; ++i) {
          acc[i][jb] += w[i][q].x * e[q].x; acc[i][jb] += w[i][q].y * e[q].y;
          acc[i][jb] += w[i][q].z * e[q].z; acc[i][jb] += w[i][q].w * e[q].w;
        }
    }

    // ---- k-reduction: 4x shfl_xor over kg (lane bits 2..5) ----
#pragma unroll
    for (int i = 0; i < 4; ++i)
#pragma unroll
      for (int j = 0; j < 4; ++j) {
        float v = acc[i][j];
        v += __shfl_xor(v, 4, 64);
        v += __shfl_xor(v, 8, 64);
        v += __shfl_xor(v, 16, 64);
        v += __shfl_xor(v, 32, 64);
        acc[i][j] = v;
      }
    if (lane < 16) {
      int kgl = lane >> 2;
      int r = rowg * 4 + kgl;
#pragma unroll
      for (int j = 0; j < 4; ++j)
        gsc[r * 8 + bbase + j] = acc[kgl][j];
    }
    __syncthreads();

    // ---- activations + sc0sc1 h post (wave 0), then sub-counter post ----
    if (tid < 64) {
      int b = tid & 7, uu = tid >> 3;
      float gi = gsc[(0 * 8 + uu) * 8 + b] + bI;
      float gf = gsc[(1 * 8 + uu) * 8 + b] + bF;
      float gg = gsc[(2 * 8 + uu) * 8 + b] + bG;
      float go = gsc[(3 * 8 + uu) * 8 + b] + bO;
      float iv = sigm(gi), fv = sigm(gf), ov = sigm(go), gv = tanhf(gg);
      c_reg = fv * c_reg + iv * gv;
      float hval = ov * tanhf(c_reg);
      int bglob = bg * 8 + b, unit = ug * 8 + uu;
      float* hd = hbuf + ((t & 1) << 14) + (bglob << 9) + unit;
      stg1fs(hd, hval);
      if (t == len) lasth[(bglob << 9) + unit] = hval;
      asm volatile("s_waitcnt vmcnt(0)" ::: "memory");   // wave0 stores at LLC
      if (tid == 0)
        __hip_atomic_fetch_add(mycnt, 1u, __ATOMIC_RELAXED, __HIP_MEMORY_SCOPE_AGENT);
    }
  }
}

// =====================================================================
// FC head
// =====================================================================
__global__ void __launch_bounds__(128)
fc_kernel(const float* __restrict__ lasth, const float* __restrict__ fcW,
          const float* __restrict__ fcb, float* __restrict__ out)
{
  int tid = threadIdx.x;
  int b = tid >> 2, n = tid & 3;
  const float4* h4 = (const float4*)(lasth + (size_t)b * 512);
  const float4* w4 = (const float4*)(fcW + (size_t)n * 512);
  float s0 = 0.f, s1 = 0.f, s2 = 0.f, s3 = 0.f;
#pragma unroll 8
  for (int k = 0; k < 128; ++k) {
    float4 a = h4[k], c = w4[k];
    s0 += a.x * c.x; s1 += a.y * c.y; s2 += a.z * c.z; s3 += a.w * c.w;
  }
  out[b * 4 + n] = fcb[n] + ((s0 + s1) + (s2 + s3));
}

// =====================================================================
// Fallback: round-2 proven persistent kernel (only if ws too small)
// =====================================================================
__device__ __forceinline__ void gl2lds16(const void* gsrc, void* ldst) {
  __builtin_amdgcn_global_load_lds(
      (const __attribute__((address_space(1))) u32*)gsrc,
      (__attribute__((address_space(3))) u32*)ldst, 16, 0, 0);
}

__global__ void __launch_bounds__(256)
lstm_persist(const int* __restrict__ xidx, const int* __restrict__ attn,
             const float* __restrict__ emb,
             const float* __restrict__ Wih, const float* __restrict__ Whh,
             const float* __restrict__ bih, const float* __restrict__ bhh,
             float* __restrict__ hbuf, float* __restrict__ lasth,
             u32* __restrict__ arrive)
{
  __shared__ __align__(16) float Wl[8][1024];
  __shared__ __align__(16) float ul[2][32][64];
  __shared__ float gsc[32][8];

  const int tid  = threadIdx.x;
  const int wg   = blockIdx.x;
  const int lane = tid & 63;
  const int wv   = tid >> 6;
  const int r    = tid & 7;
  const int bb   = tid >> 3;
  const int brl  = bb & 7;

#pragma unroll 2
  for (int i = 0; i < 8; ++i) {
    int ci = i * 256 + tid;
    int rr = ci >> 8;
    int cc = ci & 255;
    int R  = ((rr >> 1) << 9) + (wg * 2 + (rr & 1));
    const float* src = (cc < 128) ? (Wih + (size_t)R * 512 + cc * 4)
                                  : (Whh + (size_t)R * 512 + (cc - 128) * 4);
    float4 v = *(const float4*)src;
    int slot = cc ^ (rr & 7);
    *(float4*)&Wl[rr][slot * 4] = v;
  }
  float bias;
  {
    int R = ((r >> 1) << 9) + (wg * 2 + (r & 1));
    bias = bih[R] + bhh[R];
  }
  {
    int pb = tid >> 3, pc = tid & 7;
    const int4* ap = (const int4*)(attn + pb * 2048 + pc * 256);
    int s = 0;
#pragma unroll 8
    for (int k = 0; k < 64; ++k) { int4 a = ap[k]; s += a.x + a.y + a.z + a.w; }
    gsc[pb][pc] = (float)s;
  }
  __syncthreads();
  int   len_reg = 0;
  float c_reg   = 0.f;
  if (tid < 64) {
    int b2 = tid & 31;
    int s = 0;
#pragma unroll
    for (int k = 0; k < 8; ++k) s += (int)gsc[b2][k];
    len_reg = s - 1;
    if (len_reg < 0) len_reg = 2047;
  }
  __syncthreads();

  const int idx_b = 8 * wv + (lane & 7);
  int idx_cur = xidx[(size_t)idx_b * 2048];

  for (int t = 0; t < T_SEQ; ++t) {
    int idx_next = (t < T_SEQ - 1) ? xidx[(size_t)idx_b * 2048 + t + 1] : 0;
    float a0 = bias, a1 = 0.f, a2 = 0.f, a3 = 0.f;
    const float* hsrc = hbuf + (((t + 1) & 1) << 14);

    auto stageE = [&](int jt, int buf) {
#pragma unroll
      for (int q = 0; q < 2; ++q) {
        int rlq = 4 * q + (lane >> 4);
        int sc = lane & 15;
        int kc = sc ^ (rlq & 7);
        int rowg = __shfl(idx_cur, rlq, 64);
        const float* g = emb + (size_t)rowg * 512 + jt * 64 + kc * 4;
        gl2lds16(g, (void*)&ul[buf][8 * wv + 4 * q][0]);
      }
    };
    auto stageH = [&](int jt, int buf) {
#pragma unroll
      for (int q = 0; q < 2; ++q) {
        int rlq = 4 * q + (lane >> 4);
        int sc = lane & 15;
        int kc = sc ^ (rlq & 7);
        int blq = 8 * wv + rlq;
        const float* g = hsrc + (size_t)blq * 512 + jt * 64 + kc * 4;
        gl2lds16(g, (void*)&ul[buf][8 * wv + 4 * q][0]);
      }
    };
    auto computeT = [&](int jg, int buf) {
#pragma unroll
      for (int kc = 0; kc < 16; ++kc) {
        float4 uv4 = *(const float4*)&ul[buf][bb][(kc ^ brl) * 4];
        float4 wv4 = *(const float4*)&Wl[r][(((jg << 4) + kc) ^ r) * 4];
        a0 += uv4.x * wv4.x; a1 += uv4.y * wv4.y;
        a2 += uv4.z * wv4.z; a3 += uv4.w * wv4.w;
      }
    };

    stageE(0, 0);
#pragma unroll
    for (int jt = 0; jt < 8; ++jt) {
      if (jt < 7) { stageE(jt + 1, (jt + 1) & 1); asm volatile("s_waitcnt vmcnt(2)" ::: "memory"); }
      else       { asm volatile("s_waitcnt vmcnt(0)" ::: "memory"); }
      computeT(jt, jt & 1);
    }

    if (tid == 0) {
      u32 target = (u32)t << 8;
      while (__hip_atomic_load(arrive, __ATOMIC_RELAXED, __HIP_MEMORY_SCOPE_AGENT) < target)
        __builtin_amdgcn_s_sleep(2);
    }
    __syncthreads();
    __builtin_amdgcn_fence(__ATOMIC_ACQUIRE, "agent");

    stageH(0, 0);
#pragma unroll
    for (int jt = 0; jt < 8; ++jt) {
      if (jt < 7) { stageH(jt + 1, (jt + 1) & 1); asm volatile("s_waitcnt vmcnt(2)" ::: "memory"); }
      else       { asm volatile("s_waitcnt vmcnt(0)" ::: "memory"); }
      computeT(8 + jt, jt & 1);
    }

    gsc[bb][r] = a0 + a1 + a2 + a3;
    __syncthreads();
    if (tid < 64) {
      int u  = tid >> 5;
      int b2 = tid & 31;
      float gi = gsc[b2][u];
      float gf = gsc[b2][2 + u];
      float gg = gsc[b2][4 + u];
      float go = gsc[b2][6 + u];
      float iv = sigm(gi), fv = sigm(gf), ov = sigm(go);
      float gv = tanhf(gg);
      c_reg = fv * c_reg + iv * gv;
      float hv = ov * tanhf(c_reg);
      int unit = (wg << 1) + u;
      hbuf[((t & 1) << 14) + (b2 << 9) + unit] = hv;
      if (t == len_reg) lasth[(b2 << 9) + unit] = hv;
      __builtin_amdgcn_fence(__ATOMIC_RELEASE, "agent");
      if (tid == 0)
        __hip_atomic_fetch_add(arrive, 1u, __ATOMIC_RELAXED, __HIP_MEMORY_SCOPE_AGENT);
    }
    idx_cur = idx_next;
  }
}

extern "C" void kernel_launch(void* const* d_in, const int* in_sizes, int n_in,
                              void* d_out, int out_size, void* d_ws, size_t ws_size,
                              hipStream_t stream) {
  const int*   x    = (const int*)d_in[0];
  const int*   attn = (const int*)d_in[1];
  const float* emb  = (const float*)d_in[2];
  const float* Wih  = (const float*)d_in[3];
  const float* Whh  = (const float*)d_in[4];
  const float* bih  = (const float*)d_in[5];
  const float* bhh  = (const float*)d_in[6];
  const float* fcW  = (const float*)d_in[7];
  const float* fcb  = (const float*)d_in[8];
  float* out = (float*)d_out;
  char* ws = (char*)d_ws;

  if (ws_size >= WS_NEED) {
    float* hbuf  = (float*)(ws + OFF_HBUF);
    u32*   cnts  = (u32*)(ws + OFF_CNT);
    float* lasth = (float*)(ws + OFF_LASTH);

    (void)hipFuncSetAttribute((const void*)lstm_seq,
                              hipFuncAttributeMaxDynamicSharedMemorySize, DYN_LDS_BYTES);
    (void)hipMemsetAsync(ws, 0, OFF_LASTH, stream);   // hbuf + counters

    hipLaunchKernelGGL(lstm_seq, dim3(NWG), dim3(256), DYN_LDS_BYTES, stream,
                       x, attn, emb, Wih, Whh, bih, bhh, hbuf, cnts, lasth);
    hipLaunchKernelGGL(fc_kernel, dim3(1), dim3(128), 0, stream,
                       lasth, fcW, fcb, out);
  } else {
    float* hbuf   = (float*)(ws + FB_OFF_HBUF);
    u32*   arrive = (u32*)(ws + FB_OFF_ARRIVE);
    float* lasth  = (float*)(ws + FB_OFF_LASTH);
    (void)hipMemsetAsync(ws, 0, 131072 + 256, stream);
    hipLaunchKernelGGL(lstm_persist, dim3(256), dim3(256), 0, stream,
                       x, attn, emb, Wih, Whh, bih, bhh, hbuf, lasth, arrive);
    hipLaunchKernelGGL(fc_kernel, dim3(1), dim3(128), 0, stream,
                       lasth, fcW, fcb, out);
  }
}